// Round 2
// baseline (268.862 us; speedup 1.0000x reference)
//
#include <hip/hip_runtime.h>
#include <stdint.h>

#define B_ 4
#define C_ 256
#define N_ 4096
#define CQ_ 32

typedef __attribute__((ext_vector_type(8))) short short8;
typedef __attribute__((ext_vector_type(4))) float f32x4;

__device__ __forceinline__ unsigned short f2bf(float f) {
    unsigned int u = __float_as_uint(f);
    u += 0x7FFFu + ((u >> 16) & 1u);
    return (unsigned short)(u >> 16);
}

// ---------------------------------------------------------------------------
// Projection: q = Wq x + bq, k = Wk x + bk, v = Wv x + bv (1x1 convs).
// Outputs: qT,kT as (B, N, 32) bf16  (row-contiguous for MFMA frags)
//          vb   as (B, C, N)  bf16  (row-contiguous in j for PV B-frags)
// grid: B * 16 * 10 blocks of 256.  group g: 0->q, 1->k, 2..9 -> v rows (g-2)*32..+31
// ---------------------------------------------------------------------------
__global__ __launch_bounds__(256) void proj_kernel(
    const float* __restrict__ x,
    const float* __restrict__ Wq, const float* __restrict__ bq,
    const float* __restrict__ Wk, const float* __restrict__ bk,
    const float* __restrict__ Wv, const float* __restrict__ bv,
    unsigned short* __restrict__ qT, unsigned short* __restrict__ kT,
    unsigned short* __restrict__ vb)
{
    const int t = threadIdx.x;
    const int blk = blockIdx.x;
    const int g = blk % 10;
    const int itile = (blk / 10) & 15;
    const int b = blk / 160;
    const int i = itile * 256 + t;

    const float* xb = x + (size_t)b * (C_ * N_) + i;

    const float* wbase;
    const float* bbase;
    if (g == 0)      { wbase = Wq;                    bbase = bq; }
    else if (g == 1) { wbase = Wk;                    bbase = bk; }
    else             { wbase = Wv + (g - 2) * 32 * C_; bbase = bv + (g - 2) * 32; }

    float acc[32];
#pragma unroll
    for (int oo = 0; oo < 32; ++oo) acc[oo] = 0.f;

#pragma unroll 4
    for (int c = 0; c < C_; ++c) {
        float xv = xb[(size_t)c * N_];          // coalesced across threads
#pragma unroll
        for (int oo = 0; oo < 32; ++oo)
            acc[oo] = fmaf(wbase[oo * C_ + c], xv, acc[oo]);  // uniform -> s_load
    }

    if (g < 2) {
        unsigned int w[16];
#pragma unroll
        for (int oo = 0; oo < 16; ++oo)
            w[oo] = (unsigned int)f2bf(acc[2 * oo] + bbase[2 * oo]) |
                    ((unsigned int)f2bf(acc[2 * oo + 1] + bbase[2 * oo + 1]) << 16);
        unsigned short* dst = (g == 0 ? qT : kT) + ((size_t)(b * N_) + i) * 32;
        uint4* d4 = (uint4*)dst;
        d4[0] = make_uint4(w[0], w[1], w[2], w[3]);
        d4[1] = make_uint4(w[4], w[5], w[6], w[7]);
        d4[2] = make_uint4(w[8], w[9], w[10], w[11]);
        d4[3] = make_uint4(w[12], w[13], w[14], w[15]);
    } else {
        const int o0 = (g - 2) * 32;
#pragma unroll
        for (int oo = 0; oo < 32; ++oo)
            vb[((size_t)(b * C_) + o0 + oo) * N_ + i] = f2bf(acc[oo] + bbase[oo]);
    }
}

// ---------------------------------------------------------------------------
// Flash attention + epilogue: out = gamma * (softmax(QK^T/16) V^T)^T + x
// grid: 256 blocks (1/CU), 256 threads (4 waves).
// Block = (batch, 64 q-rows). Wave w: computes S/softmax for q-rows [16w,16w+16),
// then PV for channel slice [64w, 64w+64) over ALL 64 q-rows of the block.
// KV-tile = 64. V-tile staged in LDS (+8 pad), read exactly once block-wide.
// ---------------------------------------------------------------------------
__global__ __launch_bounds__(256) void attn_kernel(
    const unsigned short* __restrict__ qT, const unsigned short* __restrict__ kT,
    const unsigned short* __restrict__ vb, const float* __restrict__ x,
    const float* __restrict__ gamma, float* __restrict__ out)
{
    __shared__ unsigned short Vl[256][72];   // [c][j], padded
    __shared__ unsigned short Pl[64][72];    // [i][j] bf16 P, padded
    __shared__ float scale_l[64];            // per-row exp(m_old - m_new)
    __shared__ float sum_l[64];              // final softmax denominators

    // XCD swizzle: 256 blocks -> each batch's 64 blocks on 2 XCDs (KV L2-resident)
    const int bid = ((blockIdx.x & 7) << 5) + (blockIdx.x >> 3);
    const int b  = bid >> 6;
    const int i0 = (bid & 63) << 6;
    const int tid = threadIdx.x;
    const int wid = tid >> 6;
    const int lane = tid & 63;
    const int l15 = lane & 15;
    const int l4  = lane >> 4;

    // A-frag of Q for this wave's 16 rows: row = l15, k = 8*l4 + e
    const short8 qfrag = *(const short8*)(
        qT + ((size_t)(b * N_ + i0 + 16 * wid + l15)) * 32 + 8 * l4);

    float m_r[4], l_r[4];
#pragma unroll
    for (int r = 0; r < 4; ++r) { m_r[r] = -1e30f; l_r[r] = 0.f; }

    f32x4 acc[4][4];   // [qf][nb]: rows 16qf+4*l4+r, cols 64*wid+16*nb+l15
#pragma unroll
    for (int qf = 0; qf < 4; ++qf)
#pragma unroll
        for (int nb = 0; nb < 4; ++nb)
            acc[qf][nb] = (f32x4){0.f, 0.f, 0.f, 0.f};

    const f32x4 zero = {0.f, 0.f, 0.f, 0.f};

    for (int j0 = 0; j0 < N_; j0 += 64) {
        __syncthreads();   // prev tile's PV reads of Vl/Pl/scale_l done

        // ---- stage V tile: vb[b][c][j0..j0+63] -> Vl[c][0..63] ----
        // 256 rows x 8 chunks of 8 bf16 = 2048 uint4 stores, 8 per thread
#pragma unroll
        for (int it = 0; it < 8; ++it) {
            int idx = it * 256 + tid;
            int c = idx >> 3, ch = idx & 7;
            const uint4* src = (const uint4*)(vb + ((size_t)(b * C_ + c)) * N_ + j0 + ch * 8);
            *((uint4*)&Vl[c][ch * 8]) = *src;
        }

        // ---- S = Q K^T / 16 for own 16 rows ----
        f32x4 s[4];
#pragma unroll
        for (int f = 0; f < 4; ++f) {
            short8 kf = *(const short8*)(
                kT + ((size_t)(b * N_ + j0 + 16 * f + l15)) * 32 + 8 * l4);
            s[f] = __builtin_amdgcn_mfma_f32_16x16x32_bf16(qfrag, kf, zero, 0, 0, 0);
        }
#pragma unroll
        for (int f = 0; f < 4; ++f)
#pragma unroll
            for (int r = 0; r < 4; ++r) s[f][r] *= 0.0625f;

        // ---- online softmax (rows i = 16*wid + 4*l4 + r; j covered by f x l15) ----
        float mx[4];
#pragma unroll
        for (int r = 0; r < 4; ++r)
            mx[r] = fmaxf(fmaxf(s[0][r], s[1][r]), fmaxf(s[2][r], s[3][r]));
#pragma unroll
        for (int msk = 1; msk <= 8; msk <<= 1)
#pragma unroll
            for (int r = 0; r < 4; ++r)
                mx[r] = fmaxf(mx[r], __shfl_xor(mx[r], msk, 64));

        float sc[4], psum[4];
#pragma unroll
        for (int r = 0; r < 4; ++r) {
            float mn = fmaxf(m_r[r], mx[r]);
            sc[r] = exp2f((m_r[r] - mn) * 1.44269504f);
            m_r[r] = mn;
            psum[r] = 0.f;
        }
#pragma unroll
        for (int f = 0; f < 4; ++f)
#pragma unroll
            for (int r = 0; r < 4; ++r) {
                float p = exp2f((s[f][r] - m_r[r]) * 1.44269504f);
                s[f][r] = p;
                psum[r] += p;
            }
#pragma unroll
        for (int msk = 1; msk <= 8; msk <<= 1)
#pragma unroll
            for (int r = 0; r < 4; ++r)
                psum[r] += __shfl_xor(psum[r], msk, 64);
#pragma unroll
        for (int r = 0; r < 4; ++r)
            l_r[r] = l_r[r] * sc[r] + psum[r];

        // ---- publish P (bf16) and rescale factors ----
#pragma unroll
        for (int f = 0; f < 4; ++f)
#pragma unroll
            for (int r = 0; r < 4; ++r)
                Pl[(wid << 4) + (l4 << 2) + r][(f << 4) + l15] = f2bf(s[f][r]);
        if (l15 == 0) {
#pragma unroll
            for (int r = 0; r < 4; ++r)
                scale_l[(wid << 4) + (l4 << 2) + r] = sc[r];
        }

        __syncthreads();   // V staged + P/scale published

        // ---- rescale accumulators ----
#pragma unroll
        for (int qf = 0; qf < 4; ++qf) {
            const f32x4 scq = *(const f32x4*)&scale_l[(qf << 4) + (l4 << 2)];
#pragma unroll
            for (int nb = 0; nb < 4; ++nb)
#pragma unroll
                for (int r = 0; r < 4; ++r)
                    acc[qf][nb][r] *= scq[r];
        }

        // ---- PV: O[i][c] += P[i][j] * v[c][j] ----
        short8 vf[4][2];
#pragma unroll
        for (int nb = 0; nb < 4; ++nb)
#pragma unroll
            for (int kb = 0; kb < 2; ++kb)
                vf[nb][kb] = *(const short8*)&Vl[(wid << 6) + (nb << 4) + l15][(kb << 5) + (l4 << 3)];
#pragma unroll
        for (int qf = 0; qf < 4; ++qf) {
#pragma unroll
            for (int kb = 0; kb < 2; ++kb) {
                short8 pa = *(const short8*)&Pl[(qf << 4) + l15][(kb << 5) + (l4 << 3)];
#pragma unroll
                for (int nb = 0; nb < 4; ++nb)
                    acc[qf][nb] = __builtin_amdgcn_mfma_f32_16x16x32_bf16(pa, vf[nb][kb], acc[qf][nb], 0, 0, 0);
            }
        }
    }

    // ---- epilogue: out = gamma * acc / l + x ----
    if (l15 == 0) {
#pragma unroll
        for (int r = 0; r < 4; ++r)
            sum_l[(wid << 4) + (l4 << 2) + r] = l_r[r];
    }
    __syncthreads();

    const float gm = gamma[0];
#pragma unroll
    for (int qf = 0; qf < 4; ++qf) {
        const f32x4 ls = *(const f32x4*)&sum_l[(qf << 4) + (l4 << 2)];
        float inv[4];
#pragma unroll
        for (int r = 0; r < 4; ++r) inv[r] = 1.0f / ls[r];
#pragma unroll
        for (int nb = 0; nb < 4; ++nb) {
            const int c = (wid << 6) + (nb << 4) + l15;
            const size_t oidx = ((size_t)(b * C_ + c)) * N_ + i0 + (qf << 4) + (l4 << 2);
            const float4 xr = *(const float4*)(x + oidx);
            float4 res;
            res.x = gm * (acc[qf][nb][0] * inv[0]) + xr.x;
            res.y = gm * (acc[qf][nb][1] * inv[1]) + xr.y;
            res.z = gm * (acc[qf][nb][2] * inv[2]) + xr.z;
            res.w = gm * (acc[qf][nb][3] * inv[3]) + xr.w;
            *(float4*)(out + oidx) = res;
        }
    }
}

extern "C" void kernel_launch(void* const* d_in, const int* in_sizes, int n_in,
                              void* d_out, int out_size, void* d_ws, size_t ws_size,
                              hipStream_t stream) {
    (void)in_sizes; (void)n_in; (void)out_size; (void)ws_size;
    const float* x  = (const float*)d_in[0];
    const float* Wq = (const float*)d_in[1];
    const float* bq = (const float*)d_in[2];
    const float* Wk = (const float*)d_in[3];
    const float* bk = (const float*)d_in[4];
    const float* Wv = (const float*)d_in[5];
    const float* bv = (const float*)d_in[6];
    const float* gm = (const float*)d_in[7];
    float* out = (float*)d_out;

    unsigned short* qT = (unsigned short*)d_ws;                    // (B,N,32) bf16: 1 MB
    unsigned short* kT = qT + (size_t)B_ * N_ * CQ_;               // (B,N,32) bf16: 1 MB
    unsigned short* vb = kT + (size_t)B_ * N_ * CQ_;               // (B,C,N) bf16: 8 MB

    hipLaunchKernelGGL(proj_kernel, dim3(4 * 16 * 10), dim3(256), 0, stream,
                       x, Wq, bq, Wk, bk, Wv, bv, qT, kT, vb);
    hipLaunchKernelGGL(attn_kernel, dim3(256), dim3(256), 0, stream,
                       qT, kT, vb, x, gm, out);
}

// Round 3
// 133.824 us; speedup vs baseline: 2.0091x; 2.0091x over previous
//
#include <hip/hip_runtime.h>
#include <stdint.h>

#define B_ 4
#define C_ 256
#define N_ 4096

typedef __attribute__((ext_vector_type(8))) short short8;
typedef __attribute__((ext_vector_type(4))) float f32x4;

__device__ __forceinline__ unsigned short f2bf(float f) {
    unsigned int u = __float_as_uint(f);
    u += 0x7FFFu + ((u >> 16) & 1u);
    return (unsigned short)(u >> 16);
}

// ---------------------------------------------------------------------------
// prep: pack W -> wb[320][256] bf16 (rows 0-31 Wq/16, 32-63 Wk, 64-319 Wv),
//       biases -> bb[320] f32 (bq/16, bk, bv).  grid 320 x 64.
// ---------------------------------------------------------------------------
__global__ __launch_bounds__(64) void prep_kernel(
    const float* __restrict__ Wq, const float* __restrict__ bq,
    const float* __restrict__ Wk, const float* __restrict__ bk,
    const float* __restrict__ Wv, const float* __restrict__ bv,
    unsigned short* __restrict__ wb, float* __restrict__ bb)
{
    const int m = blockIdx.x;
    const int t = threadIdx.x;
    const float* src;
    float scale = 1.0f, bias;
    if (m < 32)      { src = Wq + m * C_;        scale = 0.0625f; bias = bq[m] * 0.0625f; }
    else if (m < 64) { src = Wk + (m - 32) * C_;                  bias = bk[m - 32]; }
    else             { src = Wv + (m - 64) * C_;                  bias = bv[m - 64]; }
    float4 v = *(const float4*)(src + t * 4);
    unsigned int lo = (unsigned int)f2bf(v.x * scale) | ((unsigned int)f2bf(v.y * scale) << 16);
    unsigned int hi = (unsigned int)f2bf(v.z * scale) | ((unsigned int)f2bf(v.w * scale) << 16);
    *(uint2*)(wb + m * C_ + t * 4) = make_uint2(lo, hi);
    if (t == 0) bb[m] = bias;
}

// ---------------------------------------------------------------------------
// proj (MFMA GEMM): D[m][n] = sum_k wb[m][k] * x[b][k][n]  (+bias)
// grid 256 = (b, n-tile of 64), 256 threads = 4 waves, wave w: m rows 80w..80w+79.
// x-tile staged in LDS bf16 [256 k][68 pad]. Outputs: qT,kT (B,N,32), vb (B,C,N).
// ---------------------------------------------------------------------------
__global__ __launch_bounds__(256) void proj_kernel(
    const float* __restrict__ x,
    const unsigned short* __restrict__ wb, const float* __restrict__ bb,
    unsigned short* __restrict__ qT, unsigned short* __restrict__ kT,
    unsigned short* __restrict__ vb)
{
    __shared__ unsigned short xs[256][68];   // +4 pad: 4-way-max banks on column reads

    const int bid = ((blockIdx.x & 7) << 5) + (blockIdx.x >> 3);
    const int b = bid >> 6, n0 = (bid & 63) << 6;
    const int tid = threadIdx.x, wid = tid >> 6, lane = tid & 63;
    const int l15 = lane & 15, l4 = lane >> 4;

    // stage x-tile: [k=256][n=64] f32 -> bf16 LDS (coalesced float4 reads)
#pragma unroll
    for (int it = 0; it < 16; ++it) {
        int idx = it * 256 + tid;
        int k = idx >> 4, n4 = (idx & 15) << 2;
        float4 v = *(const float4*)(x + ((size_t)(b * C_ + k)) * N_ + n0 + n4);
        unsigned int lo = (unsigned int)f2bf(v.x) | ((unsigned int)f2bf(v.y) << 16);
        unsigned int hi = (unsigned int)f2bf(v.z) | ((unsigned int)f2bf(v.w) << 16);
        *(uint2*)&xs[k][n4] = make_uint2(lo, hi);
    }
    __syncthreads();

    const int m0 = wid * 80;
    f32x4 acc[5][4];
#pragma unroll
    for (int mf = 0; mf < 5; ++mf)
#pragma unroll
        for (int nt = 0; nt < 4; ++nt)
            acc[mf][nt] = (f32x4){0.f, 0.f, 0.f, 0.f};

#pragma unroll
    for (int s = 0; s < 8; ++s) {
        short8 wf[5];
#pragma unroll
        for (int mf = 0; mf < 5; ++mf)
            wf[mf] = *(const short8*)(wb + (size_t)(m0 + 16 * mf + l15) * C_ + 32 * s + 8 * l4);
        short8 xf[4];
#pragma unroll
        for (int nt = 0; nt < 4; ++nt) {
#pragma unroll
            for (int e = 0; e < 8; ++e)
                xf[nt][e] = (short)xs[32 * s + 8 * l4 + e][16 * nt + l15];
        }
#pragma unroll
        for (int mf = 0; mf < 5; ++mf)
#pragma unroll
            for (int nt = 0; nt < 4; ++nt)
                acc[mf][nt] = __builtin_amdgcn_mfma_f32_16x16x32_bf16(wf[mf], xf[nt], acc[mf][nt], 0, 0, 0);
    }

    // epilogue: D row m = m0+16mf+4*l4+r, col n = n0+16nt+l15
#pragma unroll
    for (int mf = 0; mf < 5; ++mf) {
        const int mbase = m0 + 16 * mf + 4 * l4;         // + r
        const float4 b4 = *(const float4*)(bb + mbase);
        const int region = (m0 + 16 * mf) >> 5;          // 0:q 1:k >=2:v (uniform/wave)
#pragma unroll
        for (int nt = 0; nt < 4; ++nt) {
            const int n = n0 + 16 * nt + l15;
            float o0 = acc[mf][nt][0] + b4.x;
            float o1 = acc[mf][nt][1] + b4.y;
            float o2 = acc[mf][nt][2] + b4.z;
            float o3 = acc[mf][nt][3] + b4.w;
            if (region == 0) {
                unsigned int lo = (unsigned int)f2bf(o0) | ((unsigned int)f2bf(o1) << 16);
                unsigned int hi = (unsigned int)f2bf(o2) | ((unsigned int)f2bf(o3) << 16);
                *(uint2*)(qT + ((size_t)(b * N_ + n)) * 32 + mbase) = make_uint2(lo, hi);
            } else if (region == 1) {
                unsigned int lo = (unsigned int)f2bf(o0) | ((unsigned int)f2bf(o1) << 16);
                unsigned int hi = (unsigned int)f2bf(o2) | ((unsigned int)f2bf(o3) << 16);
                *(uint2*)(kT + ((size_t)(b * N_ + n)) * 32 + (mbase - 32)) = make_uint2(lo, hi);
            } else {
                const int c = mbase - 64;
                vb[((size_t)(b * C_ + c + 0)) * N_ + n] = f2bf(o0);
                vb[((size_t)(b * C_ + c + 1)) * N_ + n] = f2bf(o1);
                vb[((size_t)(b * C_ + c + 2)) * N_ + n] = f2bf(o2);
                vb[((size_t)(b * C_ + c + 3)) * N_ + n] = f2bf(o3);
            }
        }
    }
}

// ---------------------------------------------------------------------------
// attn: out = gamma * (softmax(q k^T) V^T)^T + x   (q pre-scaled by 1/16)
// grid 256 blocks (b, 64 q-rows), 512 threads = 8 waves.
// waves 0-3: QK^T + online softmax for 16 q-rows each; publish P (bf16) + scales.
// waves 4-7: double-buffered V staging (next tile) into XOR-swizzled LDS.
// all 8:     PV MFMA on 32-channel slices.  2 barriers / tile.
// ---------------------------------------------------------------------------
__global__ __launch_bounds__(512) void attn_kernel(
    const unsigned short* __restrict__ qT, const unsigned short* __restrict__ kT,
    const unsigned short* __restrict__ vb, const float* __restrict__ x,
    const float* __restrict__ gamma, float* __restrict__ out)
{
    __shared__ unsigned short Vl[2][256 * 64];  // [c][j] swizzled: slot ^= (c&7)
    __shared__ unsigned short Pl[64][72];       // [i][j] bf16 P (padded, as r2)
    __shared__ float scale_l[64];
    __shared__ float sum_l[64];

    const int bid = ((blockIdx.x & 7) << 5) + (blockIdx.x >> 3);  // batch -> 2 XCDs
    const int b = bid >> 6, i0 = (bid & 63) << 6;
    const int tid = threadIdx.x, wid = tid >> 6, lane = tid & 63;
    const int l15 = lane & 15, l4 = lane >> 4;

    f32x4 acc[4][2];
#pragma unroll
    for (int qf = 0; qf < 4; ++qf)
#pragma unroll
        for (int nb = 0; nb < 2; ++nb)
            acc[qf][nb] = (f32x4){0.f, 0.f, 0.f, 0.f};

    float m_r[4], l_r[4];
#pragma unroll
    for (int r = 0; r < 4; ++r) { m_r[r] = -1e30f; l_r[r] = 0.f; }

    const f32x4 zero = {0.f, 0.f, 0.f, 0.f};
    short8 qfrag, kf0, kf1, kf2, kf3;

    if (wid < 4) {
        qfrag = *(const short8*)(qT + ((size_t)(b * N_ + i0 + 16 * wid + l15)) * 32 + 8 * l4);
        kf0 = *(const short8*)(kT + ((size_t)(b * N_ +  0 + l15)) * 32 + 8 * l4);
        kf1 = *(const short8*)(kT + ((size_t)(b * N_ + 16 + l15)) * 32 + 8 * l4);
        kf2 = *(const short8*)(kT + ((size_t)(b * N_ + 32 + l15)) * 32 + 8 * l4);
        kf3 = *(const short8*)(kT + ((size_t)(b * N_ + 48 + l15)) * 32 + 8 * l4);
    } else {
        // prologue: stage V tile 0 into Vl[0]
        const int t2 = tid & 255;
#pragma unroll
        for (int it = 0; it < 8; ++it) {
            int q = it * 256 + t2;
            int c = q >> 3, sl = q & 7;
            uint4 v = *(const uint4*)(vb + ((size_t)(b * C_ + c)) * N_ + sl * 8);
            *(uint4*)&Vl[0][c * 64 + ((sl ^ (c & 7)) << 3)] = v;
        }
    }

    int cur = 0;
    for (int t = 0; t < 64; ++t) {
        const int jn = ((t + 1) << 6) & (N_ - 1);   // next tile (wraps harmlessly)
        if (wid < 4) {
            // prefetch next K frags
            short8 kn0 = *(const short8*)(kT + ((size_t)(b * N_ + jn +  0 + l15)) * 32 + 8 * l4);
            short8 kn1 = *(const short8*)(kT + ((size_t)(b * N_ + jn + 16 + l15)) * 32 + 8 * l4);
            short8 kn2 = *(const short8*)(kT + ((size_t)(b * N_ + jn + 32 + l15)) * 32 + 8 * l4);
            short8 kn3 = *(const short8*)(kT + ((size_t)(b * N_ + jn + 48 + l15)) * 32 + 8 * l4);

            f32x4 s[4];
            s[0] = __builtin_amdgcn_mfma_f32_16x16x32_bf16(qfrag, kf0, zero, 0, 0, 0);
            s[1] = __builtin_amdgcn_mfma_f32_16x16x32_bf16(qfrag, kf1, zero, 0, 0, 0);
            s[2] = __builtin_amdgcn_mfma_f32_16x16x32_bf16(qfrag, kf2, zero, 0, 0, 0);
            s[3] = __builtin_amdgcn_mfma_f32_16x16x32_bf16(qfrag, kf3, zero, 0, 0, 0);

            float mx[4];
#pragma unroll
            for (int r = 0; r < 4; ++r)
                mx[r] = fmaxf(fmaxf(s[0][r], s[1][r]), fmaxf(s[2][r], s[3][r]));
#pragma unroll
            for (int msk = 1; msk <= 8; msk <<= 1)
#pragma unroll
                for (int r = 0; r < 4; ++r)
                    mx[r] = fmaxf(mx[r], __shfl_xor(mx[r], msk, 64));

            float sc[4], psum[4];
#pragma unroll
            for (int r = 0; r < 4; ++r) {
                float mn = fmaxf(m_r[r], mx[r]);
                sc[r] = exp2f((m_r[r] - mn) * 1.44269504f);
                m_r[r] = mn;
                psum[r] = 0.f;
            }
#pragma unroll
            for (int f = 0; f < 4; ++f)
#pragma unroll
                for (int r = 0; r < 4; ++r) {
                    float p = exp2f((s[f][r] - m_r[r]) * 1.44269504f);
                    s[f][r] = p;
                    psum[r] += p;
                }
#pragma unroll
            for (int msk = 1; msk <= 8; msk <<= 1)
#pragma unroll
                for (int r = 0; r < 4; ++r)
                    psum[r] += __shfl_xor(psum[r], msk, 64);
#pragma unroll
            for (int r = 0; r < 4; ++r)
                l_r[r] = l_r[r] * sc[r] + psum[r];

#pragma unroll
            for (int f = 0; f < 4; ++f)
#pragma unroll
                for (int r = 0; r < 4; ++r)
                    Pl[(wid << 4) + (l4 << 2) + r][(f << 4) + l15] = f2bf(s[f][r]);
            if (l15 == 0) {
#pragma unroll
                for (int r = 0; r < 4; ++r)
                    scale_l[(wid << 4) + (l4 << 2) + r] = sc[r];
            }
            kf0 = kn0; kf1 = kn1; kf2 = kn2; kf3 = kn3;
        } else {
            // stage next V tile into Vl[cur^1]
            const int t2 = tid & 255;
            unsigned short* dst = &Vl[cur ^ 1][0];
#pragma unroll
            for (int it = 0; it < 8; ++it) {
                int q = it * 256 + t2;
                int c = q >> 3, sl = q & 7;
                uint4 v = *(const uint4*)(vb + ((size_t)(b * C_ + c)) * N_ + jn + sl * 8);
                *(uint4*)&dst[c * 64 + ((sl ^ (c & 7)) << 3)] = v;
            }
        }

        __syncthreads();   // P + scales ready; V(t+1) staged

        // rescale accumulators
#pragma unroll
        for (int qf = 0; qf < 4; ++qf) {
            const f32x4 scq = *(const f32x4*)&scale_l[(qf << 4) + (l4 << 2)];
#pragma unroll
            for (int nb = 0; nb < 2; ++nb)
#pragma unroll
                for (int r = 0; r < 4; ++r)
                    acc[qf][nb][r] *= scq[r];
        }

        // PV: channels c = 32*wid + 16*nb + l15, using V(t) from Vl[cur]
        const unsigned short* vsrc = &Vl[cur][0];
        short8 vf[2][2];
#pragma unroll
        for (int nb = 0; nb < 2; ++nb)
#pragma unroll
            for (int kb = 0; kb < 2; ++kb) {
                int c = (wid << 5) + (nb << 4) + l15;
                vf[nb][kb] = *(const short8*)&vsrc[c * 64 + ((((kb << 2) + l4) ^ (c & 7)) << 3)];
            }
#pragma unroll
        for (int qf = 0; qf < 4; ++qf) {
#pragma unroll
            for (int kb = 0; kb < 2; ++kb) {
                short8 pa = *(const short8*)&Pl[(qf << 4) + l15][(kb << 5) + (l4 << 3)];
#pragma unroll
                for (int nb = 0; nb < 2; ++nb)
                    acc[qf][nb] = __builtin_amdgcn_mfma_f32_16x16x32_bf16(pa, vf[nb][kb], acc[qf][nb], 0, 0, 0);
            }
        }

        __syncthreads();   // PV done: Pl / Vl[cur] reusable next iter
        cur ^= 1;
    }

    if (wid < 4 && l15 == 0) {
#pragma unroll
        for (int r = 0; r < 4; ++r)
            sum_l[(wid << 4) + (l4 << 2) + r] = l_r[r];
    }
    __syncthreads();

    const float gm = gamma[0];
#pragma unroll
    for (int qf = 0; qf < 4; ++qf) {
        const f32x4 ls = *(const f32x4*)&sum_l[(qf << 4) + (l4 << 2)];
        float inv[4];
#pragma unroll
        for (int r = 0; r < 4; ++r) inv[r] = 1.0f / ls[r];
#pragma unroll
        for (int nb = 0; nb < 2; ++nb) {
            const int c = (wid << 5) + (nb << 4) + l15;
            const size_t oidx = ((size_t)(b * C_ + c)) * N_ + i0 + (qf << 4) + (l4 << 2);
            const float4 xr = *(const float4*)(x + oidx);
            float4 res;
            res.x = gm * (acc[qf][nb][0] * inv[0]) + xr.x;
            res.y = gm * (acc[qf][nb][1] * inv[1]) + xr.y;
            res.z = gm * (acc[qf][nb][2] * inv[2]) + xr.z;
            res.w = gm * (acc[qf][nb][3] * inv[3]) + xr.w;
            *(float4*)(out + oidx) = res;
        }
    }
}

extern "C" void kernel_launch(void* const* d_in, const int* in_sizes, int n_in,
                              void* d_out, int out_size, void* d_ws, size_t ws_size,
                              hipStream_t stream) {
    (void)in_sizes; (void)n_in; (void)out_size; (void)ws_size;
    const float* x  = (const float*)d_in[0];
    const float* Wq = (const float*)d_in[1];
    const float* bq = (const float*)d_in[2];
    const float* Wk = (const float*)d_in[3];
    const float* bk = (const float*)d_in[4];
    const float* Wv = (const float*)d_in[5];
    const float* bv = (const float*)d_in[6];
    const float* gm = (const float*)d_in[7];
    float* out = (float*)d_out;

    char* ws = (char*)d_ws;
    unsigned short* wb = (unsigned short*)ws;                       // 320*256*2   = 160 KB
    float*          bb = (float*)(ws + 320 * 256 * 2);              // 320*4
    unsigned short* qT = (unsigned short*)(ws + 320 * 256 * 2 + 320 * 4);          // 1 MB
    unsigned short* kT = qT + (size_t)B_ * N_ * 32;                                // 1 MB
    unsigned short* vb = kT + (size_t)B_ * N_ * 32;                                // 8 MB

    hipLaunchKernelGGL(prep_kernel, dim3(320), dim3(64), 0, stream,
                       Wq, bq, Wk, bk, Wv, bv, wb, bb);
    hipLaunchKernelGGL(proj_kernel, dim3(256), dim3(256), 0, stream,
                       x, wb, bb, qT, kT, vb);
    hipLaunchKernelGGL(attn_kernel, dim3(256), dim3(512), 0, stream,
                       qT, kT, vb, x, gm, out);
}

// Round 4
// 100.362 us; speedup vs baseline: 2.6789x; 1.3334x over previous
//
#include <hip/hip_runtime.h>
#include <stdint.h>

#define B_ 4
#define C_ 256
#define N_ 4096
#define LOG2E 1.44269504088896341f

typedef __attribute__((ext_vector_type(8))) short short8;
typedef __attribute__((ext_vector_type(4))) float f32x4;

__device__ __forceinline__ unsigned short f2bf(float f) {
    unsigned int u = __float_as_uint(f);
    u += 0x7FFFu + ((u >> 16) & 1u);
    return (unsigned short)(u >> 16);
}

// pack two f32 -> bf16 pair (round-half-up; inputs are finite softmax probs)
__device__ __forceinline__ unsigned int pack_bf(float a, float b) {
    return ((__float_as_uint(a) + 0x8000u) >> 16) |
           ((__float_as_uint(b) + 0x8000u) & 0xFFFF0000u);
}

// ---------------------------------------------------------------------------
// prep: pack W -> wb[320][256] bf16 (rows 0-31 Wq*(log2e/16), 32-63 Wk, 64-319 Wv),
//       biases -> bb[320] f32.  grid 320 x 64.
// ---------------------------------------------------------------------------
__global__ __launch_bounds__(64) void prep_kernel(
    const float* __restrict__ Wq, const float* __restrict__ bq,
    const float* __restrict__ Wk, const float* __restrict__ bk,
    const float* __restrict__ Wv, const float* __restrict__ bv,
    unsigned short* __restrict__ wb, float* __restrict__ bb)
{
    const int m = blockIdx.x;
    const int t = threadIdx.x;
    const float* src;
    float scale = 1.0f, bias;
    if (m < 32)      { src = Wq + m * C_;        scale = 0.0625f * LOG2E; bias = bq[m] * 0.0625f * LOG2E; }
    else if (m < 64) { src = Wk + (m - 32) * C_;                          bias = bk[m - 32]; }
    else             { src = Wv + (m - 64) * C_;                          bias = bv[m - 64]; }
    float4 v = *(const float4*)(src + t * 4);
    unsigned int lo = (unsigned int)f2bf(v.x * scale) | ((unsigned int)f2bf(v.y * scale) << 16);
    unsigned int hi = (unsigned int)f2bf(v.z * scale) | ((unsigned int)f2bf(v.w * scale) << 16);
    *(uint2*)(wb + m * C_ + t * 4) = make_uint2(lo, hi);
    if (t == 0) bb[m] = bias;
}

// ---------------------------------------------------------------------------
// proj (MFMA GEMM): D[m][n] = sum_k wb[m][k] * x[b][k][n]  (+bias)
// grid 256 = (b, n-tile of 64), 256 threads = 4 waves, wave w: m rows 80w..80w+79.
// ---------------------------------------------------------------------------
__global__ __launch_bounds__(256) void proj_kernel(
    const float* __restrict__ x,
    const unsigned short* __restrict__ wb, const float* __restrict__ bb,
    unsigned short* __restrict__ qT, unsigned short* __restrict__ kT,
    unsigned short* __restrict__ vb)
{
    __shared__ unsigned short xs[256][68];

    const int bid = ((blockIdx.x & 7) << 5) + (blockIdx.x >> 3);
    const int b = bid >> 6, n0 = (bid & 63) << 6;
    const int tid = threadIdx.x, wid = tid >> 6, lane = tid & 63;
    const int l15 = lane & 15, l4 = lane >> 4;

#pragma unroll
    for (int it = 0; it < 16; ++it) {
        int idx = it * 256 + tid;
        int k = idx >> 4, n4 = (idx & 15) << 2;
        float4 v = *(const float4*)(x + ((size_t)(b * C_ + k)) * N_ + n0 + n4);
        unsigned int lo = (unsigned int)f2bf(v.x) | ((unsigned int)f2bf(v.y) << 16);
        unsigned int hi = (unsigned int)f2bf(v.z) | ((unsigned int)f2bf(v.w) << 16);
        *(uint2*)&xs[k][n4] = make_uint2(lo, hi);
    }
    __syncthreads();

    const int m0 = wid * 80;
    f32x4 acc[5][4];
#pragma unroll
    for (int mf = 0; mf < 5; ++mf)
#pragma unroll
        for (int nt = 0; nt < 4; ++nt)
            acc[mf][nt] = (f32x4){0.f, 0.f, 0.f, 0.f};

#pragma unroll
    for (int s = 0; s < 8; ++s) {
        short8 wf[5];
#pragma unroll
        for (int mf = 0; mf < 5; ++mf)
            wf[mf] = *(const short8*)(wb + (size_t)(m0 + 16 * mf + l15) * C_ + 32 * s + 8 * l4);
        short8 xf[4];
#pragma unroll
        for (int nt = 0; nt < 4; ++nt) {
#pragma unroll
            for (int e = 0; e < 8; ++e)
                xf[nt][e] = (short)xs[32 * s + 8 * l4 + e][16 * nt + l15];
        }
#pragma unroll
        for (int mf = 0; mf < 5; ++mf)
#pragma unroll
            for (int nt = 0; nt < 4; ++nt)
                acc[mf][nt] = __builtin_amdgcn_mfma_f32_16x16x32_bf16(wf[mf], xf[nt], acc[mf][nt], 0, 0, 0);
    }

#pragma unroll
    for (int mf = 0; mf < 5; ++mf) {
        const int mbase = m0 + 16 * mf + 4 * l4;
        const float4 b4 = *(const float4*)(bb + mbase);
        const int region = (m0 + 16 * mf) >> 5;
#pragma unroll
        for (int nt = 0; nt < 4; ++nt) {
            const int n = n0 + 16 * nt + l15;
            float o0 = acc[mf][nt][0] + b4.x;
            float o1 = acc[mf][nt][1] + b4.y;
            float o2 = acc[mf][nt][2] + b4.z;
            float o3 = acc[mf][nt][3] + b4.w;
            if (region == 0) {
                *(uint2*)(qT + ((size_t)(b * N_ + n)) * 32 + mbase) =
                    make_uint2(pack_bf(o0, o1), pack_bf(o2, o3));
            } else if (region == 1) {
                *(uint2*)(kT + ((size_t)(b * N_ + n)) * 32 + (mbase - 32)) =
                    make_uint2(pack_bf(o0, o1), pack_bf(o2, o3));
            } else {
                const int c = mbase - 64;
                vb[((size_t)(b * C_ + c + 0)) * N_ + n] = f2bf(o0);
                vb[((size_t)(b * C_ + c + 1)) * N_ + n] = f2bf(o1);
                vb[((size_t)(b * C_ + c + 2)) * N_ + n] = f2bf(o2);
                vb[((size_t)(b * C_ + c + 3)) * N_ + n] = f2bf(o3);
            }
        }
    }
}

// ---------------------------------------------------------------------------
// attn: producer-consumer flash attention.
// grid 256 blocks (b, 64 q-rows), 512 threads = 8 waves.
// waves 0-3 (QK): swapped QK^T (S^T via mfma(K,Q)) + online softmax for 16 q-rows
//                 each; publish P(bf16)+scale into double-buffered LDS.
// waves 4-7 (PV): consume P(t-1), V-frags direct from L2 (reg ping-pong),
//                 32 MFMA/tile each. One barrier per tile.
// ---------------------------------------------------------------------------
__global__ __launch_bounds__(512, 2) void attn_kernel(
    const unsigned short* __restrict__ qT, const unsigned short* __restrict__ kT,
    const unsigned short* __restrict__ vbuf, const float* __restrict__ x,
    const float* __restrict__ gamma, float* __restrict__ out)
{
    __shared__ unsigned short Pl[2][64][72];   // [buf][q][j] bf16
    __shared__ float sc_l[2][64];              // [buf][q] rescale factors
    __shared__ float sum_l[64];                // final denominators

    const int bid = ((blockIdx.x & 7) << 5) + (blockIdx.x >> 3);  // batch -> 2 XCDs
    const int b = bid >> 6, i0 = (bid & 63) << 6;
    const int tid = threadIdx.x, wid = tid >> 6, lane = tid & 63;
    const int l15 = lane & 15, l4 = lane >> 4;
    const f32x4 zero = {0.f, 0.f, 0.f, 0.f};

    if (wid < 4) {
        // ================= QK / softmax producer =================
        const short8 qfrag = *(const short8*)(
            qT + ((size_t)(b * N_ + i0 + 16 * wid + l15)) * 32 + 8 * l4);
        const unsigned short* kbase = kT + ((size_t)b * N_ + l15) * 32 + 8 * l4;

        short8 ka[4], kb_[4];
        _Pragma("unroll")
        for (int f = 0; f < 4; ++f)
            ka[f] = *(const short8*)(kbase + (size_t)(16 * f) * 32);

        float m = -1e30f, l = 0.f;

#define QK_BODY(T, KC, KN)                                                        \
  {                                                                               \
    if ((T) < 63) {                                                               \
      _Pragma("unroll")                                                           \
      for (int f = 0; f < 4; ++f)                                                 \
        KN[f] = *(const short8*)(kbase + (size_t)(((T) + 1) * 64 + 16 * f) * 32); \
    }                                                                             \
    f32x4 sv[4];                                                                  \
    _Pragma("unroll")                                                             \
    for (int f = 0; f < 4; ++f)                                                   \
      sv[f] = __builtin_amdgcn_mfma_f32_16x16x32_bf16(KC[f], qfrag, zero, 0, 0, 0);\
    float mx = sv[0][0];                                                          \
    _Pragma("unroll")                                                             \
    for (int f = 0; f < 4; ++f) {                                                 \
      _Pragma("unroll")                                                           \
      for (int r = 0; r < 4; ++r) mx = fmaxf(mx, sv[f][r]);                       \
    }                                                                             \
    mx = fmaxf(mx, __shfl_xor(mx, 16, 64));                                       \
    mx = fmaxf(mx, __shfl_xor(mx, 32, 64));                                       \
    const float mn = fmaxf(m, mx);                                                \
    const float scf = exp2f(m - mn);                                              \
    m = mn;                                                                       \
    float ps = 0.f;                                                               \
    _Pragma("unroll")                                                             \
    for (int f = 0; f < 4; ++f) {                                                 \
      _Pragma("unroll")                                                           \
      for (int r = 0; r < 4; ++r) { sv[f][r] = exp2f(sv[f][r] - mn); ps += sv[f][r]; } \
    }                                                                             \
    ps += __shfl_xor(ps, 16, 64);                                                 \
    ps += __shfl_xor(ps, 32, 64);                                                 \
    l = l * scf + ps;                                                             \
    unsigned short* prow = &Pl[(T) & 1][16 * wid + l15][4 * l4];                  \
    _Pragma("unroll")                                                             \
    for (int f = 0; f < 4; ++f)                                                   \
      *(uint2*)(prow + 16 * f) = make_uint2(pack_bf(sv[f][0], sv[f][1]),          \
                                            pack_bf(sv[f][2], sv[f][3]));         \
    if (l4 == 0) sc_l[(T) & 1][16 * wid + l15] = scf;                             \
  }

        for (int u = 0; u < 32; ++u) {
            QK_BODY(2 * u, ka, kb_)
            __syncthreads();
            QK_BODY(2 * u + 1, kb_, ka)
            __syncthreads();
        }
        if (l4 == 0) sum_l[16 * wid + l15] = l;
        __syncthreads();
        // QK waves exit
    } else {
        // ================= PV consumer =================
        const int c0 = (wid - 4) << 6;
        const unsigned short* vrow[4];
        _Pragma("unroll")
        for (int nb = 0; nb < 4; ++nb)
            vrow[nb] = vbuf + ((size_t)(b * C_ + c0 + 16 * nb + l15)) * N_ + 8 * l4;

        f32x4 acc[4][4];
        _Pragma("unroll")
        for (int qf = 0; qf < 4; ++qf) {
            _Pragma("unroll")
            for (int nb = 0; nb < 4; ++nb)
                acc[qf][nb] = (f32x4){0.f, 0.f, 0.f, 0.f};
        }

        short8 va_[4][2], vb2_[4][2];

#define PV_LOAD(DST, T)                                                           \
    {                                                                             \
      _Pragma("unroll")                                                           \
      for (int nb = 0; nb < 4; ++nb) {                                            \
        _Pragma("unroll")                                                         \
        for (int kb = 0; kb < 2; ++kb)                                            \
          DST[nb][kb] = *(const short8*)(vrow[nb] + (T) * 64 + kb * 32);          \
      }                                                                           \
    }

#define PV_BODY(T, VC, VN)                                                        \
  {                                                                               \
    if ((T) >= 1 && (T) < 64) PV_LOAD(VN, (T))                                    \
    const int bf = ((T) + 1) & 1; /* == (T-1)&1 */                                \
    short8 pa[4][2];                                                              \
    _Pragma("unroll")                                                             \
    for (int qf = 0; qf < 4; ++qf) {                                              \
      _Pragma("unroll")                                                           \
      for (int kb = 0; kb < 2; ++kb)                                              \
        pa[qf][kb] = *(const short8*)&Pl[bf][16 * qf + l15][kb * 32 + 8 * l4];    \
    }                                                                             \
    _Pragma("unroll")                                                             \
    for (int qf = 0; qf < 4; ++qf) {                                              \
      const f32x4 scv = *(const f32x4*)&sc_l[bf][16 * qf + 4 * l4];               \
      _Pragma("unroll")                                                           \
      for (int nb = 0; nb < 4; ++nb) {                                            \
        _Pragma("unroll")                                                         \
        for (int r = 0; r < 4; ++r) acc[qf][nb][r] *= scv[r];                     \
      }                                                                           \
    }                                                                             \
    __builtin_amdgcn_s_setprio(1);                                                \
    _Pragma("unroll")                                                             \
    for (int qf = 0; qf < 4; ++qf) {                                              \
      _Pragma("unroll")                                                           \
      for (int kb = 0; kb < 2; ++kb) {                                            \
        _Pragma("unroll")                                                         \
        for (int nb = 0; nb < 4; ++nb)                                            \
          acc[qf][nb] = __builtin_amdgcn_mfma_f32_16x16x32_bf16(pa[qf][kb], VC[nb][kb], acc[qf][nb], 0, 0, 0); \
      }                                                                           \
    }                                                                             \
    __builtin_amdgcn_s_setprio(0);                                                \
  }

        PV_LOAD(vb2_, 0)          // prologue: tile 0
        __syncthreads();          // barrier for t=0
        for (int u = 0; u < 32; ++u) {
            PV_BODY(2 * u + 1, vb2_, va_)
            __syncthreads();
            PV_BODY(2 * u + 2, va_, vb2_)
            __syncthreads();
        }

        // epilogue: out = gamma/l * acc + x
        const float gm = gamma[0];
        _Pragma("unroll")
        for (int qf = 0; qf < 4; ++qf) {
            const f32x4 lv = *(const f32x4*)&sum_l[16 * qf + 4 * l4];
            float inv[4];
            _Pragma("unroll")
            for (int r = 0; r < 4; ++r) inv[r] = gm / lv[r];
            _Pragma("unroll")
            for (int nb = 0; nb < 4; ++nb) {
                const size_t oidx = ((size_t)(b * C_ + c0 + 16 * nb + l15)) * N_
                                    + i0 + 16 * qf + 4 * l4;
                const float4 xr = *(const float4*)(x + oidx);
                float4 res;
                res.x = acc[qf][nb][0] * inv[0] + xr.x;
                res.y = acc[qf][nb][1] * inv[1] + xr.y;
                res.z = acc[qf][nb][2] * inv[2] + xr.z;
                res.w = acc[qf][nb][3] * inv[3] + xr.w;
                *(float4*)(out + oidx) = res;
            }
        }
    }
}

extern "C" void kernel_launch(void* const* d_in, const int* in_sizes, int n_in,
                              void* d_out, int out_size, void* d_ws, size_t ws_size,
                              hipStream_t stream) {
    (void)in_sizes; (void)n_in; (void)out_size; (void)ws_size;
    const float* x  = (const float*)d_in[0];
    const float* Wq = (const float*)d_in[1];
    const float* bq = (const float*)d_in[2];
    const float* Wk = (const float*)d_in[3];
    const float* bk = (const float*)d_in[4];
    const float* Wv = (const float*)d_in[5];
    const float* bv = (const float*)d_in[6];
    const float* gm = (const float*)d_in[7];
    float* out = (float*)d_out;

    char* ws = (char*)d_ws;
    unsigned short* wb = (unsigned short*)ws;                                // 160 KB
    float*          bb = (float*)(ws + 320 * 256 * 2);                       // 1.25 KB
    unsigned short* qT = (unsigned short*)(ws + 320 * 256 * 2 + 320 * 4);    // 1 MB
    unsigned short* kT = qT + (size_t)B_ * N_ * 32;                          // 1 MB
    unsigned short* vb = kT + (size_t)B_ * N_ * 32;                          // 8 MB

    hipLaunchKernelGGL(prep_kernel, dim3(320), dim3(64), 0, stream,
                       Wq, bq, Wk, bk, Wv, bv, wb, bb);
    hipLaunchKernelGGL(proj_kernel, dim3(256), dim3(256), 0, stream,
                       x, wb, bb, qT, kT, vb);
    hipLaunchKernelGGL(attn_kernel, dim3(256), dim3(512), 0, stream,
                       qT, kT, vb, x, gm, out);
}